// Round 3
// baseline (701.070 us; speedup 1.0000x reference)
//
#include <hip/hip_runtime.h>
#include <math.h>

#define N_ROWS 131072
#define D 512
#define BLOCKS 4096
#define WPB 4
#define NWAVES (BLOCKS * WPB)                 // 16384 waves
#define ROWS_PER_WAVE (N_ROWS / NWAVES)       // 8
#define N_IT (ROWS_PER_WAVE / 2)              // 4 iterations x 2 rows
#define EPS 1e-6f

// numerically stable softplus
__device__ __forceinline__ float softplusf(float x) {
    if (x > 0.0f) return x + log1pf(__expf(-x));
    return log1pf(__expf(x));
}

__global__ __launch_bounds__(256, 4) void binloss_main(
    const float* __restrict__ o1, const float* __restrict__ o2,
    const int* __restrict__ target,
    float* __restrict__ sums, int* __restrict__ icnt,
    unsigned int* __restrict__ done, float* __restrict__ out) {

    const int lane = threadIdx.x & 63;
    const int wave = threadIdx.x >> 6;
    const int gwave = blockIdx.x * WPB + wave;

    float posAcc = 0.0f, negAcc = 0.0f;
    int posCnt = 0;

    // pipeline registers: current (c) and next (n), 2 rows each
    float4 ca0, ca1, cb0, cb1, ca2, ca3, cb2, cb3;
    float4 na0, na1, nb0, nb1, na2, na3, nb2, nb3;
    int ct0, ct1, nt0, nt1;

    // prologue: load iteration 0 (rows 2*gwave, 2*gwave+1)
    {
        const int r0 = 2 * gwave;
        const float4* p1 = (const float4*)(o1 + (size_t)r0 * D);
        const float4* p2 = (const float4*)(o2 + (size_t)r0 * D);
        ca0 = p1[lane];        ca1 = p1[lane + 64];       // row r0, o1
        cb0 = p2[lane];        cb1 = p2[lane + 64];       // row r0, o2
        ca2 = p1[lane + 128];  ca3 = p1[lane + 192];      // row r0+1, o1
        cb2 = p2[lane + 128];  cb3 = p2[lane + 192];      // row r0+1, o2
        ct0 = target[r0];      ct1 = target[r0 + 1];
    }

    #pragma unroll
    for (int it = 0; it < N_IT; ++it) {
        // prefetch next iteration's 2 rows (8 independent float4 loads)
        if (it + 1 < N_IT) {
            const int r0 = 2 * (gwave + (it + 1) * NWAVES);
            const float4* p1 = (const float4*)(o1 + (size_t)r0 * D);
            const float4* p2 = (const float4*)(o2 + (size_t)r0 * D);
            na0 = p1[lane];        na1 = p1[lane + 64];
            nb0 = p2[lane];        nb1 = p2[lane + 64];
            na2 = p1[lane + 128];  na3 = p1[lane + 192];
            nb2 = p2[lane + 128];  nb3 = p2[lane + 192];
            nt0 = target[r0];      nt1 = target[r0 + 1];
        }

        // partials for current 2 rows
        float dotA = ca0.x*cb0.x + ca0.y*cb0.y + ca0.z*cb0.z + ca0.w*cb0.w
                   + ca1.x*cb1.x + ca1.y*cb1.y + ca1.z*cb1.z + ca1.w*cb1.w;
        float s1A  = ca0.x*ca0.x + ca0.y*ca0.y + ca0.z*ca0.z + ca0.w*ca0.w
                   + ca1.x*ca1.x + ca1.y*ca1.y + ca1.z*ca1.z + ca1.w*ca1.w;
        float s2A  = cb0.x*cb0.x + cb0.y*cb0.y + cb0.z*cb0.z + cb0.w*cb0.w
                   + cb1.x*cb1.x + cb1.y*cb1.y + cb1.z*cb1.z + cb1.w*cb1.w;
        float dotB = ca2.x*cb2.x + ca2.y*cb2.y + ca2.z*cb2.z + ca2.w*cb2.w
                   + ca3.x*cb3.x + ca3.y*cb3.y + ca3.z*cb3.z + ca3.w*cb3.w;
        float s1B  = ca2.x*ca2.x + ca2.y*ca2.y + ca2.z*ca2.z + ca2.w*ca2.w
                   + ca3.x*ca3.x + ca3.y*ca3.y + ca3.z*ca3.z + ca3.w*ca3.w;
        float s2B  = cb2.x*cb2.x + cb2.y*cb2.y + cb2.z*cb2.z + cb2.w*cb2.w
                   + cb3.x*cb3.x + cb3.y*cb3.y + cb3.z*cb3.z + cb3.w*cb3.w;

        // 6 independent butterfly chains
        #pragma unroll
        for (int off = 32; off > 0; off >>= 1) {
            dotA += __shfl_xor(dotA, off);
            s1A  += __shfl_xor(s1A, off);
            s2A  += __shfl_xor(s2A, off);
            dotB += __shfl_xor(dotB, off);
            s1B  += __shfl_xor(s1B, off);
            s2B  += __shfl_xor(s2B, off);
        }

        if (lane == 0) {
            // branchless epilogue, both rows
            float dA = dotA / fmaxf(sqrtf(s1A) * sqrtf(s2A), EPS);
            float dB = dotB / fmaxf(sqrtf(s1B) * sqrtf(s2B), EPS);
            float pA = (ct0 == 1) ? 1.0f : 0.0f;
            float pB = (ct1 == 1) ? 1.0f : 0.0f;
            posAcc += pA * 4.0f * softplusf(-0.5f * (dA - 0.5f))
                    + pB * 4.0f * softplusf(-0.5f * (dB - 0.5f));
            negAcc += (1.0f - pA) * 0.04f * softplusf(50.0f * (dA - 2.0f))
                    + (1.0f - pB) * 0.04f * softplusf(50.0f * (dB - 2.0f));
            posCnt += (ct0 == 1) + (ct1 == 1);
        }

        // rotate pipeline
        ca0 = na0; ca1 = na1; cb0 = nb0; cb1 = nb1;
        ca2 = na2; ca3 = na3; cb2 = nb2; cb3 = nb3;
        ct0 = nt0; ct1 = nt1;
    }

    // block reduction -> atomics -> fused finalize in last block
    __shared__ float sPos[WPB], sNeg[WPB];
    __shared__ int sCnt[WPB];
    if (lane == 0) { sPos[wave] = posAcc; sNeg[wave] = negAcc; sCnt[wave] = posCnt; }
    __syncthreads();
    if (threadIdx.x == 0) {
        float p = sPos[0] + sPos[1] + sPos[2] + sPos[3];
        float n = sNeg[0] + sNeg[1] + sNeg[2] + sNeg[3];
        int c = sCnt[0] + sCnt[1] + sCnt[2] + sCnt[3];
        atomicAdd(&sums[0], p);
        atomicAdd(&sums[1], n);
        atomicAdd(&icnt[0], c);
        __threadfence();
        unsigned int old = atomicAdd(done, 1u);
        if (old == (unsigned int)(gridDim.x - 1)) {
            __threadfence();
            float ps = __hip_atomic_load(&sums[0], __ATOMIC_RELAXED, __HIP_MEMORY_SCOPE_AGENT);
            float ns = __hip_atomic_load(&sums[1], __ATOMIC_RELAXED, __HIP_MEMORY_SCOPE_AGENT);
            int np = __hip_atomic_load(&icnt[0], __ATOMIC_RELAXED, __HIP_MEMORY_SCOPE_AGENT);
            int nn = N_ROWS - np;
            out[0] = ps / (float)(np > 1 ? np : 1) + ns / (float)(nn > 1 ? nn : 1);
        }
    }
}

extern "C" void kernel_launch(void* const* d_in, const int* in_sizes, int n_in,
                              void* d_out, int out_size, void* d_ws, size_t ws_size,
                              hipStream_t stream) {
    const float* o1 = (const float*)d_in[0];
    const float* o2 = (const float*)d_in[1];
    const int* tgt = (const int*)d_in[2];
    float* out = (float*)d_out;
    float* sums = (float*)d_ws;
    int* cnt = (int*)((char*)d_ws + 8);
    unsigned int* done = (unsigned int*)((char*)d_ws + 12);

    hipMemsetAsync(d_ws, 0, 16, stream);
    binloss_main<<<BLOCKS, 256, 0, stream>>>(o1, o2, tgt, sums, cnt, done, out);
}

// Round 4
// 538.192 us; speedup vs baseline: 1.3026x; 1.3026x over previous
//
#include <hip/hip_runtime.h>
#include <math.h>

#define N_ROWS 131072
#define D 512
#define BLOCKS 512
#define WPB 4
#define NWAVES (BLOCKS * WPB)                  // 2048 waves
#define ROWS_PER_WAVE (N_ROWS / NWAVES)        // 64
#define N_IT (ROWS_PER_WAVE / 2)               // 32 iterations x 2 rows
#define EPS 1e-6f

// s_waitcnt imm (gfx9 encoding): lgkmcnt=0xF (no wait), expcnt=0x7 (no wait), vmcnt=N
#define WAIT_VM(N) __builtin_amdgcn_s_waitcnt(0x0F70 | ((N) & 0xF) | ((((N) >> 4) & 3) << 14))

// async 16B/lane global->LDS DMA; in-flight tracked by vmcnt, zero VGPR cost
#define GLD16(gp, lp) __builtin_amdgcn_global_load_lds(                         \
    (const __attribute__((address_space(1))) unsigned int*)(gp),                \
    (__attribute__((address_space(3))) unsigned int*)(lp), 16, 0, 0)

__device__ __forceinline__ float softplusf(float x) {
    if (x > 0.0f) return x + log1pf(__expf(-x));
    return log1pf(__expf(x));
}

// stage 4KB (2 contiguous rows of one input) as 4 x 1KB DMA chunks
__device__ __forceinline__ void stage4k(const float* __restrict__ g, float* l, int lane) {
    #pragma unroll
    for (int c = 0; c < 4; ++c)
        GLD16(g + c * 256 + lane * 4, l + c * 256 + lane * 4);
}

__global__ __launch_bounds__(256) void binloss_main(
    const float* __restrict__ o1, const float* __restrict__ o2,
    const int* __restrict__ target,
    float* __restrict__ sums, int* __restrict__ icnt,
    unsigned int* __restrict__ done, float* __restrict__ out) {

    // [wave][dbuf][input][2 rows * 512 floats] = 4*2*2*1024*4B = 64 KB
    __shared__ __align__(16) float lds[WPB][2][2][1024];
    __shared__ float sPos[WPB], sNeg[WPB];
    __shared__ int sCnt[WPB];

    const int lane = threadIdx.x & 63;
    const int wave = threadIdx.x >> 6;
    const int gwave = blockIdx.x * WPB + wave;
    const int rowBase = gwave * ROWS_PER_WAVE;
    const int sub = lane & 31;       // lane within row-group of 32
    const int rl = lane >> 5;        // which of the 2 rows this lane reduces

    // one coalesced load: lane l holds target of the wave's l-th row
    const int myT = target[rowBase + lane];

    // prologue: stage iteration 0 into buffer 0
    stage4k(o1 + (size_t)rowBase * D, &lds[wave][0][0][0], lane);
    stage4k(o2 + (size_t)rowBase * D, &lds[wave][0][1][0], lane);

    float posAcc = 0.0f, negAcc = 0.0f;
    int posCnt = 0;

    for (int k = 0; k < N_IT; ++k) {
        const int b = k & 1;
        if (k + 1 < N_IT) {
            // issue next tile's 8 DMAs, then wait until only those 8 remain
            const size_t nr = (size_t)(rowBase + 2 * (k + 1)) * D;
            stage4k(o1 + nr, &lds[wave][1 - b][0][0], lane);
            stage4k(o2 + nr, &lds[wave][1 - b][1][0], lane);
            WAIT_VM(8);
        } else {
            WAIT_VM(0);
        }

        const float* A = &lds[wave][b][0][rl * 512];
        const float* B = &lds[wave][b][1][rl * 512];
        float dot = 0.0f, s1 = 0.0f, s2 = 0.0f;
        #pragma unroll
        for (int j = 0; j < 4; ++j) {
            float4 a = *(const float4*)(A + sub * 4 + j * 128);
            float4 v = *(const float4*)(B + sub * 4 + j * 128);
            dot += a.x * v.x + a.y * v.y + a.z * v.z + a.w * v.w;
            s1  += a.x * a.x + a.y * a.y + a.z * a.z + a.w * a.w;
            s2  += v.x * v.x + v.y * v.y + v.z * v.z + v.w * v.w;
        }

        // reduce across the 32 lanes of each row-group
        #pragma unroll
        for (int off = 16; off > 0; off >>= 1) {
            dot += __shfl_xor(dot, off);
            s1  += __shfl_xor(s1, off);
            s2  += __shfl_xor(s2, off);
        }

        const int t0 = __shfl(myT, 2 * k);
        const int t1 = __shfl(myT, 2 * k + 1);
        if (sub == 0) {
            float d = dot / fmaxf(sqrtf(s1) * sqrtf(s2), EPS);
            int t = rl ? t1 : t0;
            if (t == 1) { posAcc += 4.0f * softplusf(-0.5f * (d - 0.5f)); posCnt++; }
            else        { negAcc += 0.04f * softplusf(50.0f * (d - 2.0f)); }
        }
    }

    // wave-level final reduce (only lanes 0 and 32 hold nonzero)
    #pragma unroll
    for (int off = 32; off > 0; off >>= 1) {
        posAcc += __shfl_xor(posAcc, off);
        negAcc += __shfl_xor(negAcc, off);
        posCnt += __shfl_xor(posCnt, off);
    }

    if (lane == 0) { sPos[wave] = posAcc; sNeg[wave] = negAcc; sCnt[wave] = posCnt; }
    __syncthreads();
    if (threadIdx.x == 0) {
        float p = sPos[0] + sPos[1] + sPos[2] + sPos[3];
        float n = sNeg[0] + sNeg[1] + sNeg[2] + sNeg[3];
        int c = sCnt[0] + sCnt[1] + sCnt[2] + sCnt[3];
        atomicAdd(&sums[0], p);
        atomicAdd(&sums[1], n);
        atomicAdd(&icnt[0], c);
        __threadfence();
        unsigned int old = atomicAdd(done, 1u);
        if (old == (unsigned int)(gridDim.x - 1)) {
            __threadfence();
            float ps = __hip_atomic_load(&sums[0], __ATOMIC_RELAXED, __HIP_MEMORY_SCOPE_AGENT);
            float ns = __hip_atomic_load(&sums[1], __ATOMIC_RELAXED, __HIP_MEMORY_SCOPE_AGENT);
            int np = __hip_atomic_load(&icnt[0], __ATOMIC_RELAXED, __HIP_MEMORY_SCOPE_AGENT);
            int nn = N_ROWS - np;
            out[0] = ps / (float)(np > 1 ? np : 1) + ns / (float)(nn > 1 ? nn : 1);
        }
    }
}

extern "C" void kernel_launch(void* const* d_in, const int* in_sizes, int n_in,
                              void* d_out, int out_size, void* d_ws, size_t ws_size,
                              hipStream_t stream) {
    const float* o1 = (const float*)d_in[0];
    const float* o2 = (const float*)d_in[1];
    const int* tgt = (const int*)d_in[2];
    float* out = (float*)d_out;
    float* sums = (float*)d_ws;
    int* cnt = (int*)((char*)d_ws + 8);
    unsigned int* done = (unsigned int*)((char*)d_ws + 12);

    hipMemsetAsync(d_ws, 0, 16, stream);
    binloss_main<<<BLOCKS, 256, 0, stream>>>(o1, o2, tgt, sums, cnt, done, out);
}